// Round 7
// baseline (469.466 us; speedup 1.0000x reference)
//
#include <hip/hip_runtime.h>
#include <hip/hip_bf16.h>

#define NEG_INF -9.0e15f
#define BAR_MAGIC 0x5AFE1000u

using u16 = unsigned short;
using u64 = unsigned long long;

__device__ __forceinline__ float b2f(__hip_bfloat16 v) { return __bfloat162float(v); }
__device__ __forceinline__ float ldv(const float* p, int i) { return p[i]; }
__device__ __forceinline__ float ldv(const __hip_bfloat16* p, int i) { return __bfloat162float(p[i]); }

__device__ __forceinline__ void async16(const void* g, void* l) {
    __builtin_amdgcn_global_load_lds(
        (__attribute__((address_space(1))) void*)(g),
        (__attribute__((address_space(3))) void*)(l), 16, 0, 0);
}

// ---- fine-grained cross-XCD payload ops: system-scope relaxed atomics -----
// On gfx950 these compile to sc0|sc1 loads/stores that bypass L1/L2 and hit
// the shared L3 coherence point directly. NO buffer_wbl2 / buffer_inv needed
// anywhere (round-6 lesson: 512 blocks x 4 phases of wbl2+inv = ~280 µs).
__device__ __forceinline__ void st_sys64(float* p, float2 v) {
    u64 u; __builtin_memcpy(&u, &v, 8);
    __hip_atomic_store((u64*)p, u, __ATOMIC_RELAXED, __HIP_MEMORY_SCOPE_SYSTEM);
}
__device__ __forceinline__ float2 ld_sys64(const float* p) {
    u64 u = __hip_atomic_load((u64*)p, __ATOMIC_RELAXED, __HIP_MEMORY_SCOPE_SYSTEM);
    float2 v; __builtin_memcpy(&v, &u, 8); return v;
}
__device__ __forceinline__ void st_sys32(float* p, float v) {
    __hip_atomic_store(p, v, __ATOMIC_RELAXED, __HIP_MEMORY_SCOPE_SYSTEM);
}
__device__ __forceinline__ float ld_sys32(const float* p) {
    return __hip_atomic_load((float*)p, __ATOMIC_RELAXED, __HIP_MEMORY_SCOPE_SYSTEM);
}

// wave-level dtype sniff (uniform per wave): bf16 weights -> sane exponents.
__device__ __forceinline__ int sniff(const void* wnode) {
    const u16* w = (const u16*)wnode;
    int lane = threadIdx.x & 63;
    u16 u = w[2 * lane];
    int e = (u >> 7) & 0xFF;
    unsigned long long m = __ballot(e >= 100 && e <= 140);
    return __popcll(m) >= 48;
}

// ===========================================================================
// Device bodies shared by the fused (cooperative) kernel and the fallback
// multi-kernel path. Compute cores are the round-1 HARNESS-VERIFIED bodies;
// only the cross-block load/store instructions changed (sys-atomics).
// ===========================================================================

// GAT phase: h = x@W[l] (+ first-layer nf@Wn+b), s1 = h@a1, s2 = h@a2.
// Block covers rows row0..row0+7. smem needs 43008 B.
template <int IS_BF>
__device__ __forceinline__ void gat_body(
    char* smem, int t, int row0, int l, int first,
    const float* __restrict__ x, const void* __restrict__ gat_W,
    const void* __restrict__ gat_a,
    const void* __restrict__ nf, const void* __restrict__ Wn_raw,
    const void* __restrict__ bn,
    float* __restrict__ hw, float* __restrict__ s1w, float* __restrict__ s2w) {
    float* xsT = (float*)smem;            // 10240 B: [k(256)][row(8) pad 10]
    const int tx = t & 63, w = t >> 6;
    const int c0 = 4 * tx;
    float acc0[4], acc1[4];

    if (IS_BF) {
        u16* Wb0 = (u16*)(smem + 10240);  // 2 x 16384 B double buffer
        const u16* Wl = (const u16*)gat_W + (size_t)l * 65536;
        auto stage_rows = [&](const u16* src, int r0, int nr, int buf) {
            const char* g = (const char*)src + (size_t)r0 * 512;
            char* lp = (char*)(Wb0 + buf * 8192);
            int bytes = nr * 512;
            for (int off = t * 16; off < bytes; off += 4096)
                async16(g + off, lp + off);
        };
        auto tile_compute = [&](int buf, int k0, int nr) {
            const u16* Wp = Wb0 + buf * 8192;
            #pragma unroll 8
            for (int kk = 0; kk < nr; ++kk) {
                uint2 wv = *(const uint2*)(Wp + kk * 256 + c0);
                float w0 = __uint_as_float(wv.x << 16);
                float w1 = __uint_as_float(wv.x & 0xffff0000u);
                float w2 = __uint_as_float(wv.y << 16);
                float w3 = __uint_as_float(wv.y & 0xffff0000u);
                float2 xp = *(const float2*)&xsT[(k0 + kk) * 10 + 2 * w];
                acc0[0] += xp.x * w0; acc0[1] += xp.x * w1;
                acc0[2] += xp.x * w2; acc0[3] += xp.x * w3;
                acc1[0] += xp.y * w0; acc1[1] += xp.y * w1;
                acc1[2] += xp.y * w2; acc1[3] += xp.y * w3;
            }
        };
        int pb;
        if (first) {
            const u16* Wnl = (const u16*)Wn_raw;
            stage_rows(Wnl, 0, 32, 0);
            const u16* nfu = (const u16*)nf;
            for (int i = t; i < 624; i += 256) {
                int r = i / 78, k = i - r * 78;
                xsT[k * 10 + r] = __uint_as_float(((unsigned)nfu[(row0 + r) * 78 + k]) << 16);
            }
            const __hip_bfloat16* bnb = (const __hip_bfloat16*)bn;
            #pragma unroll
            for (int j = 0; j < 4; ++j) { acc0[j] = b2f(bnb[c0 + j]); acc1[j] = acc0[j]; }
            __syncthreads();
            stage_rows(Wnl, 32, 32, 1);
            tile_compute(0, 0, 32);
            __syncthreads();
            stage_rows(Wnl, 64, 14, 0);
            tile_compute(1, 32, 32);
            __syncthreads();
            stage_rows(Wl, 0, 32, 1);
            tile_compute(0, 64, 14);
            __syncthreads();
            #pragma unroll
            for (int j = 0; j < 4; ++j) {
                xsT[(c0 + j) * 10 + 2 * w]     = acc0[j];
                xsT[(c0 + j) * 10 + 2 * w + 1] = acc1[j];
            }
            __syncthreads();
            pb = 1;
        } else {
            stage_rows(Wl, 0, 32, 0);
            int r = t >> 5, cb = (t & 31) * 8;
            const float4* xp = (const float4*)(x + (size_t)(row0 + r) * 256 + cb);
            float4 f0 = xp[0], f1 = xp[1];
            xsT[(cb + 0) * 10 + r] = f0.x; xsT[(cb + 1) * 10 + r] = f0.y;
            xsT[(cb + 2) * 10 + r] = f0.z; xsT[(cb + 3) * 10 + r] = f0.w;
            xsT[(cb + 4) * 10 + r] = f1.x; xsT[(cb + 5) * 10 + r] = f1.y;
            xsT[(cb + 6) * 10 + r] = f1.z; xsT[(cb + 7) * 10 + r] = f1.w;
            __syncthreads();
            pb = 0;
        }
        #pragma unroll
        for (int j = 0; j < 4; ++j) { acc0[j] = 0.f; acc1[j] = 0.f; }
        for (int tt = 0; tt < 8; ++tt) {
            if (tt < 7) stage_rows(Wl, 32 * (tt + 1), 32, pb ^ 1);
            tile_compute(pb, 32 * tt, 32);
            __syncthreads();
            pb ^= 1;
        }
        const __hip_bfloat16* ga = (const __hip_bfloat16*)gat_a + (size_t)l * 512;
        float d10 = 0.f, d20 = 0.f, d11 = 0.f, d21 = 0.f;
        #pragma unroll
        for (int j = 0; j < 4; ++j) {
            float a1v = b2f(ga[c0 + j]), a2v = b2f(ga[256 + c0 + j]);
            d10 += acc0[j] * a1v; d20 += acc0[j] * a2v;
            d11 += acc1[j] * a1v; d21 += acc1[j] * a2v;
        }
        #pragma unroll
        for (int off = 1; off < 64; off <<= 1) {
            d10 += __shfl_xor(d10, off, 64); d20 += __shfl_xor(d20, off, 64);
            d11 += __shfl_xor(d11, off, 64); d21 += __shfl_xor(d21, off, 64);
        }
        if (tx == 0) {
            st_sys32(&s1w[row0 + 2 * w], d10);     st_sys32(&s2w[row0 + 2 * w], d20);
            st_sys32(&s1w[row0 + 2 * w + 1], d11); st_sys32(&s2w[row0 + 2 * w + 1], d21);
        }
        st_sys64(&hw[(size_t)(row0 + 2 * w) * 256 + c0],     (float2){acc0[0], acc0[1]});
        st_sys64(&hw[(size_t)(row0 + 2 * w) * 256 + c0 + 2], (float2){acc0[2], acc0[3]});
        st_sys64(&hw[(size_t)(row0 + 2 * w + 1) * 256 + c0],     (float2){acc1[0], acc1[1]});
        st_sys64(&hw[(size_t)(row0 + 2 * w + 1) * 256 + c0 + 2], (float2){acc1[2], acc1[3]});
    } else {
        // f32 fallback (correct, unoptimized)
        const float* Wlf = (const float*)gat_W + (size_t)l * 65536;
        const float* gaf = (const float*)gat_a + (size_t)l * 512;
        if (first) {
            const float* nff = (const float*)nf;
            for (int i = t; i < 624; i += 256) {
                int r = i / 78, k = i - r * 78;
                xsT[k * 10 + r] = nff[(row0 + r) * 78 + k];
            }
            __syncthreads();
            const float* Wnf = (const float*)Wn_raw;
            const float* bnf = (const float*)bn;
            #pragma unroll
            for (int j = 0; j < 4; ++j) { acc0[j] = bnf[c0 + j]; acc1[j] = acc0[j]; }
            for (int k = 0; k < 78; ++k) {
                float4 wf = *(const float4*)(Wnf + k * 256 + c0);
                float2 xp = *(const float2*)&xsT[k * 10 + 2 * w];
                acc0[0] += xp.x * wf.x; acc0[1] += xp.x * wf.y;
                acc0[2] += xp.x * wf.z; acc0[3] += xp.x * wf.w;
                acc1[0] += xp.y * wf.x; acc1[1] += xp.y * wf.y;
                acc1[2] += xp.y * wf.z; acc1[3] += xp.y * wf.w;
            }
            __syncthreads();
            #pragma unroll
            for (int j = 0; j < 4; ++j) {
                xsT[(c0 + j) * 10 + 2 * w]     = acc0[j];
                xsT[(c0 + j) * 10 + 2 * w + 1] = acc1[j];
            }
            __syncthreads();
        } else {
            int r = t >> 5, cb = (t & 31) * 8;
            const float4* xp = (const float4*)(x + (size_t)(row0 + r) * 256 + cb);
            float4 f0 = xp[0], f1 = xp[1];
            xsT[(cb + 0) * 10 + r] = f0.x; xsT[(cb + 1) * 10 + r] = f0.y;
            xsT[(cb + 2) * 10 + r] = f0.z; xsT[(cb + 3) * 10 + r] = f0.w;
            xsT[(cb + 4) * 10 + r] = f1.x; xsT[(cb + 5) * 10 + r] = f1.y;
            xsT[(cb + 6) * 10 + r] = f1.z; xsT[(cb + 7) * 10 + r] = f1.w;
            __syncthreads();
        }
        #pragma unroll
        for (int j = 0; j < 4; ++j) { acc0[j] = 0.f; acc1[j] = 0.f; }
        #pragma unroll 4
        for (int k = 0; k < 256; ++k) {
            float4 wf = *(const float4*)(Wlf + k * 256 + c0);
            float2 xp = *(const float2*)&xsT[k * 10 + 2 * w];
            acc0[0] += xp.x * wf.x; acc0[1] += xp.x * wf.y;
            acc0[2] += xp.x * wf.z; acc0[3] += xp.x * wf.w;
            acc1[0] += xp.y * wf.x; acc1[1] += xp.y * wf.y;
            acc1[2] += xp.y * wf.z; acc1[3] += xp.y * wf.w;
        }
        float d10 = 0.f, d20 = 0.f, d11 = 0.f, d21 = 0.f;
        #pragma unroll
        for (int j = 0; j < 4; ++j) {
            float a1v = gaf[c0 + j], a2v = gaf[256 + c0 + j];
            d10 += acc0[j] * a1v; d20 += acc0[j] * a2v;
            d11 += acc1[j] * a1v; d21 += acc1[j] * a2v;
        }
        #pragma unroll
        for (int off = 1; off < 64; off <<= 1) {
            d10 += __shfl_xor(d10, off, 64); d20 += __shfl_xor(d20, off, 64);
            d11 += __shfl_xor(d11, off, 64); d21 += __shfl_xor(d21, off, 64);
        }
        if (tx == 0) {
            st_sys32(&s1w[row0 + 2 * w], d10);     st_sys32(&s2w[row0 + 2 * w], d20);
            st_sys32(&s1w[row0 + 2 * w + 1], d11); st_sys32(&s2w[row0 + 2 * w + 1], d21);
        }
        st_sys64(&hw[(size_t)(row0 + 2 * w) * 256 + c0],     (float2){acc0[0], acc0[1]});
        st_sys64(&hw[(size_t)(row0 + 2 * w) * 256 + c0 + 2], (float2){acc0[2], acc0[3]});
        st_sys64(&hw[(size_t)(row0 + 2 * w + 1) * 256 + c0],     (float2){acc1[0], acc1[1]});
        st_sys64(&hw[(size_t)(row0 + 2 * w + 1) * 256 + c0 + 2], (float2){acc1[2], acc1[3]});
    }
}

// ATTN phase: softmax(mask(leaky(s1+s2))) @ h. b = batch, s = slice (0..15).
// smem needs 74752 B. h is staged via SYSTEM-scope (L3-bypass) loads into a
// register double buffer (16 x 8B per thread per 32-row chunk), then written
// to LDS — same linear LDS layout as the old async16 path, so the compute
// loop is byte-identical to the round-1 proven code.
__device__ __forceinline__ void attn_body(
    char* smem, int t, int b, int s,
    const float* __restrict__ hw, const float* __restrict__ s1w,
    const float* __restrict__ s2w, const int* __restrict__ adj,
    float* __restrict__ x, float* __restrict__ gpart, int do_pool) {
    float (*att_t)[10] = (float (*)[10])smem;                 // 5120 B
    float* hbuf = (float*)(smem + 5120);                      // 65536 B
    float (*pool_red)[256] = (float (*)[256])(smem + 70656);  // 4096 B
    const int i0 = s << 3;
    const int w = t >> 6, lane = t & 63;
    const float* hb = hw + (size_t)b * 32768;
    const int ph = s & 3;
    float2 reg[16];
    {   // prefetch chunk ph (rows ph*32..+31, 32 KB) into regs; in flight
        // under the softmax computation below
        const float* g = hb + ph * 8192 + t * 32;
        #pragma unroll
        for (int i = 0; i < 16; ++i) reg[i] = ld_sys64(g + 2 * i);
    }
    {
        int cc0 = lane, cc1 = lane + 64;
        int ir0 = i0 + 2 * w, ir1 = ir0 + 1;
        const int* a0 = adj + (size_t)(b * 128 + ir0) * 128;
        const int* a1 = adj + (size_t)(b * 128 + ir1) * 128;
        int m00 = a0[cc0], m01 = a0[cc1], m10 = a1[cc0], m11 = a1[cc1];
        float sv0 = ld_sys32(&s1w[b * 128 + ir0]), sv1 = ld_sys32(&s1w[b * 128 + ir1]);
        float t0 = ld_sys32(&s2w[b * 128 + cc0]),  t1 = ld_sys32(&s2w[b * 128 + cc1]);
        float e00 = sv0 + t0; e00 = (e00 >= 0.f) ? e00 : 0.2f * e00;
        float e01 = sv0 + t1; e01 = (e01 >= 0.f) ? e01 : 0.2f * e01;
        float e10 = sv1 + t0; e10 = (e10 >= 0.f) ? e10 : 0.2f * e10;
        float e11 = sv1 + t1; e11 = (e11 >= 0.f) ? e11 : 0.2f * e11;
        float v00 = (m00 > 0) ? e00 : NEG_INF;
        float v01 = (m01 > 0) ? e01 : NEG_INF;
        float v10 = (m10 > 0) ? e10 : NEG_INF;
        float v11 = (m11 > 0) ? e11 : NEG_INF;
        float mx0 = fmaxf(v00, v01), mx1 = fmaxf(v10, v11);
        #pragma unroll
        for (int off = 1; off < 64; off <<= 1) {
            mx0 = fmaxf(mx0, __shfl_xor(mx0, off, 64));
            mx1 = fmaxf(mx1, __shfl_xor(mx1, off, 64));
        }
        float p00 = __expf(v00 - mx0), p01 = __expf(v01 - mx0);
        float p10 = __expf(v10 - mx1), p11 = __expf(v11 - mx1);
        float sm0 = p00 + p01, sm1 = p10 + p11;
        #pragma unroll
        for (int off = 1; off < 64; off <<= 1) {
            sm0 += __shfl_xor(sm0, off, 64);
            sm1 += __shfl_xor(sm1, off, 64);
        }
        float inv0 = 1.0f / sm0, inv1 = 1.0f / sm1;
        att_t[cc0][2 * w]     = p00 * inv0;
        att_t[cc1][2 * w]     = p01 * inv0;
        att_t[cc0][2 * w + 1] = p10 * inv1;
        att_t[cc1][2 * w + 1] = p11 * inv1;
    }
    __syncthreads();   // att_t ready
    int tx = t & 63, ty = t >> 6;
    float ac0[4] = {0.f, 0.f, 0.f, 0.f}, ac1[4] = {0.f, 0.f, 0.f, 0.f};
    for (int c = 0; c < 4; ++c) {
        {   // commit staged regs (chunk c) to hbuf[c&1]
            float* lb = hbuf + (c & 1) * 8192 + t * 32;
            #pragma unroll
            for (int i = 0; i < 16; ++i) *(float2*)(lb + 2 * i) = reg[i];
        }
        __syncthreads();   // hbuf[c&1] visible block-wide
        if (c < 3) {       // prefetch chunk c+1 into regs under the compute
            const float* g = hb + (((c + 1 + ph) & 3) * 8192) + t * 32;
            #pragma unroll
            for (int i = 0; i < 16; ++i) reg[i] = ld_sys64(g + 2 * i);
        }
        const float* hc = hbuf + (c & 1) * 8192;
        const int jb = ((c + ph) & 3) * 32;
        #pragma unroll 4
        for (int jj = 0; jj < 32; ++jj) {
            float4 hv = *(const float4*)&hc[jj * 256 + 4 * tx];
            float2 ap = *(const float2*)&att_t[jb + jj][2 * ty];
            ac0[0] += ap.x * hv.x; ac0[1] += ap.x * hv.y;
            ac0[2] += ap.x * hv.z; ac0[3] += ap.x * hv.w;
            ac1[0] += ap.y * hv.x; ac1[1] += ap.y * hv.y;
            ac1[2] += ap.y * hv.z; ac1[3] += ap.y * hv.w;
        }
        __syncthreads();
    }
    if (!do_pool) {
        float4 o0 = {fmaxf(ac0[0],0.f), fmaxf(ac0[1],0.f), fmaxf(ac0[2],0.f), fmaxf(ac0[3],0.f)};
        float4 o1 = {fmaxf(ac1[0],0.f), fmaxf(ac1[1],0.f), fmaxf(ac1[2],0.f), fmaxf(ac1[3],0.f)};
        // x is block-local (same block writes then reads next layer): plain
        *(float4*)&x[(size_t)(b * 128 + i0 + 2 * ty)     * 256 + 4 * tx] = o0;
        *(float4*)&x[(size_t)(b * 128 + i0 + 2 * ty + 1) * 256 + 4 * tx] = o1;
        __syncthreads();   // LDS free for caller's next phase
    } else {
        float4 pr = {(fmaxf(ac0[0],0.f) + fmaxf(ac1[0],0.f)) * (1.f/128.f),
                     (fmaxf(ac0[1],0.f) + fmaxf(ac1[1],0.f)) * (1.f/128.f),
                     (fmaxf(ac0[2],0.f) + fmaxf(ac1[2],0.f)) * (1.f/128.f),
                     (fmaxf(ac0[3],0.f) + fmaxf(ac1[3],0.f)) * (1.f/128.f)};
        *(float4*)&pool_red[ty][4 * tx] = pr;
        __syncthreads();
        if (t < 64) {
            float4 r0 = ((const float4*)&pool_red[0][0])[t];
            float4 r1 = ((const float4*)&pool_red[1][0])[t];
            float4 r2 = ((const float4*)&pool_red[2][0])[t];
            float4 r3 = ((const float4*)&pool_red[3][0])[t];
            float4 o = {r0.x+r1.x+r2.x+r3.x, r0.y+r1.y+r2.y+r3.y,
                        r0.z+r1.z+r2.z+r3.z, r0.w+r1.w+r2.w+r3.w};
            float* gp = &gpart[((size_t)b * 16 + s) * 256 + 4 * t];
            st_sys64(gp,     (float2){o.x, o.y});      // cross-block -> head
            st_sys64(gp + 2, (float2){o.z, o.w});
        }
        __syncthreads();
    }
}

// head: pool MLPs + concat + out MLP (round-1 proven body; gpart via sys-load)
template <typename T>
__device__ __forceinline__ void head_body(
    int b, int t, const float* __restrict__ gpart,
    const T* scaf, const T* W_sc, const T* b_sc,
    const T* gp_w1, const T* gp_b1, const T* gp_w2, const T* gp_b2,
    const T* out_w1, const T* out_b1, const T* out_w2, const T* out_b2,
    float* gin_s, float* sproj, float* scaf_s,
    float* red1, float* red2, float* z1g, float* z1s,
    float* cvec, float* hdn, float* outv) {
    float g = 0.f;
    #pragma unroll
    for (int gg = 0; gg < 16; ++gg) g += ld_sys32(&gpart[((size_t)b * 16 + gg) * 256 + t]);
    gin_s[t] = g;
    if (t < 20) scaf_s[t] = ldv(scaf, b * 20 + t);
    __syncthreads();
    {
        float sa = ldv(b_sc, t);
        #pragma unroll
        for (int k = 0; k < 20; ++k) sa += scaf_s[k] * ldv(W_sc, k * 256 + t);
        sproj[t] = sa;
    }
    __syncthreads();
    {
        int j = t & 127, khalf = t >> 7;
        int k0 = khalf * 128;
        float a1 = 0.f, a2 = 0.f;
        #pragma unroll 16
        for (int kk = 0; kk < 128; ++kk) {
            int k = k0 + kk;
            float wv = ldv(gp_w1, k * 128 + j);
            a1 += gin_s[k] * wv;
            a2 += sproj[k] * wv;
        }
        red1[t] = a1; red2[t] = a2;
    }
    __syncthreads();
    if (t < 128) {
        float bb = ldv(gp_b1, t);
        z1g[t] = fmaxf(bb + red1[t] + red1[t + 128], 0.f);
        z1s[t] = fmaxf(bb + red2[t] + red2[t + 128], 0.f);
    }
    __syncthreads();
    {
        int j = t & 63, q = t >> 6;
        int k0 = q * 32;
        float a1 = 0.f, a2 = 0.f;
        #pragma unroll
        for (int kk = 0; kk < 32; ++kk) {
            int k = k0 + kk;
            float wv = ldv(gp_w2, k * 64 + j);
            a1 += z1g[k] * wv;
            a2 += z1s[k] * wv;
        }
        red1[t] = a1; red2[t] = a2;
    }
    __syncthreads();
    if (t < 64) {
        float bb = ldv(gp_b2, t);
        cvec[t]      = fmaxf(bb + red1[t] + red1[t + 64] + red1[t + 128] + red1[t + 192], 0.f);
        cvec[64 + t] = fmaxf(bb + red2[t] + red2[t + 64] + red2[t + 128] + red2[t + 192], 0.f);
    }
    __syncthreads();
    {
        int j = t & 127, khalf = t >> 7;
        int k0 = khalf * 64;
        float a = 0.f;
        #pragma unroll 16
        for (int kk = 0; kk < 64; ++kk) {
            int k = k0 + kk;
            a += cvec[k] * ldv(out_w1, k * 128 + j);
        }
        red1[t] = a;
    }
    __syncthreads();
    if (t < 128) hdn[t] = fmaxf(ldv(out_b1, t) + red1[t] + red1[t + 128], 0.f);
    __syncthreads();
    if (t < 13) {
        float a = ldv(out_b2, t);
        #pragma unroll 16
        for (int k = 0; k < 128; ++k) a += hdn[k] * ldv(out_w2, k * 13 + t);
        outv[t] = a;
    }
}

__device__ __forceinline__ void head_dispatch(
    char* smem, int isbf, int b, int t, const float* gpart,
    const void* scaf, const void* W_sc, const void* b_sc,
    const void* gp_w1, const void* gp_b1, const void* gp_w2, const void* gp_b2,
    const void* out_w1, const void* out_b1, const void* out_w2, const void* out_b2,
    void* out) {
    float* gin_s = (float*)smem;
    float* sproj = (float*)(smem + 1024);
    float* red1  = (float*)(smem + 2048);
    float* red2  = (float*)(smem + 3072);
    float* z1g   = (float*)(smem + 4096);
    float* z1s   = (float*)(smem + 4608);
    float* cvec  = (float*)(smem + 5120);
    float* hdn   = (float*)(smem + 5632);
    float* outv  = (float*)(smem + 6144);
    float* scaf_s= (float*)(smem + 6208);
    if (isbf) {
        head_body<__hip_bfloat16>(b, t, gpart,
            (const __hip_bfloat16*)scaf, (const __hip_bfloat16*)W_sc, (const __hip_bfloat16*)b_sc,
            (const __hip_bfloat16*)gp_w1, (const __hip_bfloat16*)gp_b1,
            (const __hip_bfloat16*)gp_w2, (const __hip_bfloat16*)gp_b2,
            (const __hip_bfloat16*)out_w1, (const __hip_bfloat16*)out_b1,
            (const __hip_bfloat16*)out_w2, (const __hip_bfloat16*)out_b2,
            gin_s, sproj, scaf_s, red1, red2, z1g, z1s, cvec, hdn, outv);
    } else {
        head_body<float>(b, t, gpart,
            (const float*)scaf, (const float*)W_sc, (const float*)b_sc,
            (const float*)gp_w1, (const float*)gp_b1,
            (const float*)gp_w2, (const float*)gp_b2,
            (const float*)out_w1, (const float*)out_b1,
            (const float*)out_w2, (const float*)out_b2,
            gin_s, sproj, scaf_s, red1, red2, z1g, z1s, cvec, hdn, outv);
    }
    __syncthreads();
    if (t < 13) {
        if (isbf) ((__hip_bfloat16*)out)[b * 13 + t] = __float2bfloat16(outv[t]);
        else      ((float*)out)[b * 13 + t] = outv[t];
    }
}

// ===========================================================================
// Per-batch 16-block flag barrier — ZERO cache-maintenance version.
// Payload travels via sys-atomics (L3 direct), so no release/acquire fences
// are needed at all: __syncthreads() drains each wave's sc-stores to L3
// (vmcnt(0) before s_barrier), then one relaxed system flag store publishes;
// waiters spin with relaxed system loads (L3 reads, no invalidates).
// Poison-safe: (v-MAGIC) > 3 reads as "not arrived". Deadlock-free: coop
// launch guarantees co-residency. Bounded spin = visible failure, no hang.
// ===========================================================================
__device__ __forceinline__ void batch_barrier(unsigned* flags, int b, int s,
                                              int t, unsigned phase) {
    __syncthreads();                 // all waves' sys-stores at L3
    if (t == 0)
        __hip_atomic_store(&flags[(b << 4) + s], BAR_MAGIC + phase,
                           __ATOMIC_RELAXED, __HIP_MEMORY_SCOPE_SYSTEM);
    if (t < 16) {
        int spins = 0;
        while (true) {
            unsigned v = __hip_atomic_load(&flags[(b << 4) + t],
                                           __ATOMIC_RELAXED, __HIP_MEMORY_SCOPE_SYSTEM);
            unsigned d = v - BAR_MAGIC;
            if (d >= phase && d <= 3u) break;   // poison -> huge d -> waits
            __builtin_amdgcn_s_sleep(1);
            if (++spins > (1 << 20)) break;     // bail visibly, never hang
        }
    }
    __syncthreads();
}

// ===========================================================================
// Cooperative fused kernel: gat -> per-batch barrier -> attn, x3 layers, then
// per-batch signal -> head. 512 blocks x 256 thr; blk = s*32 + b. h/s1/s2
// ping-pong by layer parity => one barrier per layer. Coop launch is used
// ONLY for its co-residency guarantee — no grid.sync (~200 µs each, round 4).
// ===========================================================================
__global__ __launch_bounds__(256, 2) void k_fused(
    const void* __restrict__ nf, const void* __restrict__ Wn_raw,
    const void* __restrict__ bn,
    const void* __restrict__ gat_W, const void* __restrict__ gat_a,
    const int* __restrict__ adj,
    float* __restrict__ x,
    float* __restrict__ hA, float* __restrict__ hB,
    float* __restrict__ s1A, float* __restrict__ s1B,
    float* __restrict__ s2A, float* __restrict__ s2B,
    float* __restrict__ gpart, unsigned* __restrict__ flags,
    const void* __restrict__ scaf,
    const void* __restrict__ W_sc, const void* __restrict__ b_sc,
    const void* __restrict__ gp_w1, const void* __restrict__ gp_b1,
    const void* __restrict__ gp_w2, const void* __restrict__ gp_b2,
    const void* __restrict__ out_w1, const void* __restrict__ out_b1,
    const void* __restrict__ out_w2, const void* __restrict__ out_b2,
    void* __restrict__ out) {
    __shared__ __align__(16) char smem[74752];
    const int t = threadIdx.x;
    const int blk = blockIdx.x;
    const int b = blk & 31;
    const int s = blk >> 5;
    const int row0 = b * 128 + s * 8;
    const int isbf = sniff(Wn_raw);

    for (int l = 0; l < 3; ++l) {
        float* hw  = (l & 1) ? hB : hA;
        float* s1w = (l & 1) ? s1B : s1A;
        float* s2w = (l & 1) ? s2B : s2A;
        if (isbf)
            gat_body<1>(smem, t, row0, l, l == 0, x, gat_W, gat_a, nf, Wn_raw, bn, hw, s1w, s2w);
        else
            gat_body<0>(smem, t, row0, l, l == 0, x, gat_W, gat_a, nf, Wn_raw, bn, hw, s1w, s2w);

        batch_barrier(flags, b, s, t, (unsigned)l);   // h/s2 of batch b at L3

        attn_body(smem, t, b, s, hw, s1w, s2w, adj, x, gpart, (l == 2) ? 1 : 0);
    }

    // signal gpart slice ready (phase 3); only head blocks wait
    __syncthreads();
    if (t == 0)
        __hip_atomic_store(&flags[(b << 4) + s], BAR_MAGIC + 3u,
                           __ATOMIC_RELAXED, __HIP_MEMORY_SCOPE_SYSTEM);
    if (blk < 32) {
        if (t < 16) {
            int spins = 0;
            while (true) {
                unsigned v = __hip_atomic_load(&flags[(blk << 4) + t],
                                               __ATOMIC_RELAXED, __HIP_MEMORY_SCOPE_SYSTEM);
                if (v - BAR_MAGIC == 3u) break;
                __builtin_amdgcn_s_sleep(1);
                if (++spins > (1 << 20)) break;
            }
        }
        __syncthreads();
        head_dispatch(smem, isbf, blk, t, gpart, scaf, W_sc, b_sc,
                      gp_w1, gp_b1, gp_w2, gp_b2,
                      out_w1, out_b1, out_w2, out_b2, out);
    }
}

// ===========================================================================
// Fallback kernels (round-1 harness-verified structure, via shared bodies)
// ===========================================================================
__global__ __launch_bounds__(256) void k_gat(
    const float* __restrict__ x, const void* __restrict__ gat_W,
    const void* __restrict__ gat_a, int layer,
    const void* __restrict__ nf, const void* __restrict__ Wn_raw,
    const void* __restrict__ bn, int first,
    float* __restrict__ h, float* __restrict__ s1, float* __restrict__ s2) {
    __shared__ __align__(16) char smem[43008];
    const int t = threadIdx.x;
    const int row0 = blockIdx.x * 8;
    if (sniff(Wn_raw))
        gat_body<1>(smem, t, row0, layer, first, x, gat_W, gat_a, nf, Wn_raw, bn, h, s1, s2);
    else
        gat_body<0>(smem, t, row0, layer, first, x, gat_W, gat_a, nf, Wn_raw, bn, h, s1, s2);
}

__global__ __launch_bounds__(256) void k_attn(
    const float* __restrict__ h, const float* __restrict__ s1,
    const float* __restrict__ s2, const int* __restrict__ adj,
    float* __restrict__ x, float* __restrict__ gpart, int do_pool) {
    __shared__ __align__(16) char smem[74752];
    int blk = blockIdx.x, b = blk >> 4, s = blk & 15;
    attn_body(smem, threadIdx.x, b, s, h, s1, s2, adj, x, gpart, do_pool);
}

__global__ __launch_bounds__(256) void k_head(
    const float* __restrict__ gpart, const void* __restrict__ scaf,
    const void* __restrict__ W_sc, const void* __restrict__ b_sc,
    const void* __restrict__ gp_w1, const void* __restrict__ gp_b1,
    const void* __restrict__ gp_w2, const void* __restrict__ gp_b2,
    const void* __restrict__ out_w1, const void* __restrict__ out_b1,
    const void* __restrict__ out_w2, const void* __restrict__ out_b2,
    void* __restrict__ out, const void* __restrict__ Wn) {
    __shared__ __align__(16) char smem[8192];
    head_dispatch(smem, sniff(Wn), blockIdx.x, threadIdx.x, gpart, scaf, W_sc, b_sc,
                  gp_w1, gp_b1, gp_w2, gp_b2, out_w1, out_b1, out_w2, out_b2, out);
}

extern "C" void kernel_launch(void* const* d_in, const int* in_sizes, int n_in,
                              void* d_out, int out_size, void* d_ws, size_t ws_size,
                              hipStream_t stream) {
    (void)in_sizes; (void)n_in; (void)out_size; (void)ws_size;
    const void* nf     = d_in[0];
    const int*  adj    = (const int*)d_in[2];
    const void* scaf   = d_in[3];
    const void* W_node = d_in[4];
    const void* b_node = d_in[5];
    const void* gat_W  = d_in[6];
    const void* gat_a  = d_in[7];
    const void* W_sc   = d_in[8];
    const void* b_sc   = d_in[9];
    const void* gp_w1  = d_in[10];
    const void* gp_b1  = d_in[11];
    const void* gp_w2  = d_in[12];
    const void* gp_b2  = d_in[13];
    const void* out_w1 = d_in[14];
    const void* out_b1 = d_in[15];
    const void* out_w2 = d_in[16];
    const void* out_b2 = d_in[17];

    float* ws    = (float*)d_ws;
    float* x     = ws;                      // 1,048,576 f32
    float* hA    = ws + 1048576;            // 1,048,576 f32
    float* hB    = ws + 2097152;            // 1,048,576 f32
    float* s1A   = ws + 3145728;            // 4096
    float* s2A   = ws + 3149824;            // 4096
    float* s1B   = ws + 3153920;            // 4096
    float* s2B   = ws + 3158016;            // 4096
    float* gpart = ws + 3162112;            // 131,072
    unsigned* flags = (unsigned*)(ws + 3293184);  // 512 u32
    void* out    = d_out;

    void* args[] = {
        (void*)&nf, (void*)&W_node, (void*)&b_node, (void*)&gat_W, (void*)&gat_a,
        (void*)&adj, (void*)&x, (void*)&hA, (void*)&hB,
        (void*)&s1A, (void*)&s1B, (void*)&s2A, (void*)&s2B, (void*)&gpart,
        (void*)&flags,
        (void*)&scaf, (void*)&W_sc, (void*)&b_sc,
        (void*)&gp_w1, (void*)&gp_b1, (void*)&gp_w2, (void*)&gp_b2,
        (void*)&out_w1, (void*)&out_b1, (void*)&out_w2, (void*)&out_b2,
        (void*)&out
    };
    hipError_t e = hipLaunchCooperativeKernel((const void*)k_fused, dim3(512), dim3(256),
                                              args, 0, stream);
    if (e != hipSuccess) {
        (void)hipGetLastError();   // clear sticky error, use proven multi-kernel path
        for (int l = 0; l < 3; ++l) {
            k_gat<<<512, 256, 0, stream>>>(x, gat_W, gat_a, l,
                                           nf, W_node, b_node, (l == 0) ? 1 : 0,
                                           hA, s1A, s2A);
            k_attn<<<512, 256, 0, stream>>>(hA, s1A, s2A, adj, x, gpart, (l == 2) ? 1 : 0);
        }
        k_head<<<32, 256, 0, stream>>>(gpart, scaf, W_sc, b_sc, gp_w1, gp_b1, gp_w2, gp_b2,
                                       out_w1, out_b1, out_w2, out_b2, d_out, W_node);
    }
}

// Round 9
// 206.869 us; speedup vs baseline: 2.2694x; 2.2694x over previous
//
#include <hip/hip_runtime.h>
#include <hip/hip_bf16.h>

#define NEG_INF -9.0e15f

using u16 = unsigned short;

__device__ __forceinline__ float b2f(__hip_bfloat16 v) { return __bfloat162float(v); }
__device__ __forceinline__ float ldv(const float* p, int i) { return p[i]; }
__device__ __forceinline__ float ldv(const __hip_bfloat16* p, int i) { return __bfloat162float(p[i]); }

__device__ __forceinline__ void async16(const void* g, void* l) {
    __builtin_amdgcn_global_load_lds(
        (__attribute__((address_space(1))) void*)(g),
        (__attribute__((address_space(3))) void*)(l), 16, 0, 0);
}

// wave-level dtype sniff (uniform per wave): bf16 weights -> sane exponents.
__device__ __forceinline__ int sniff(const void* wnode) {
    const u16* w = (const u16*)wnode;
    int lane = threadIdx.x & 63;
    u16 u = w[2 * lane];
    int e = (u >> 7) & 0xFF;
    unsigned long long m = __ballot(e >= 100 && e <= 140);
    return __popcll(m) >= 48;
}

// ===========================================================================
// Building blocks — round-1 HARNESS-VERIFIED bodies, split so that the
// attn->gat block-local handoff can pass x through registers+LDS (no global
// x buffer, no custom sync; kernel boundaries provide all cross-block
// coherence, which rounds 4-7 proved is cheaper than any in-kernel scheme).
// ===========================================================================

// gat main loop + epilogue. Assumes xsT[k][r] (stride 10) is populated and
// (for bf16) W tile 0 is staged into Wbuf[pb0] and drained (caller issued a
// __syncthreads() after stage). Computes h rows row0..row0+7 and s1/s2.
template <int IS_BF>
__device__ __forceinline__ void gat_core(
    char* smem, int t, int row0, int pb0,
    const void* __restrict__ gat_W, const void* __restrict__ gat_a, int l,
    float* __restrict__ hw, float* __restrict__ s1w, float* __restrict__ s2w) {
    float* xsT = (float*)smem;
    const int tx = t & 63, w = t >> 6;
    const int c0 = 4 * tx;
    float acc0[4], acc1[4];
    #pragma unroll
    for (int j = 0; j < 4; ++j) { acc0[j] = 0.f; acc1[j] = 0.f; }

    if (IS_BF) {
        u16* Wb0 = (u16*)(smem + 10240);
        const u16* Wl = (const u16*)gat_W + (size_t)l * 65536;
        auto stage_rows = [&](int r0, int nr, int buf) {
            const char* g = (const char*)Wl + (size_t)r0 * 512;
            char* lp = (char*)(Wb0 + buf * 8192);
            int bytes = nr * 512;
            for (int off = t * 16; off < bytes; off += 4096)
                async16(g + off, lp + off);
        };
        int pb = pb0;
        for (int tt = 0; tt < 8; ++tt) {
            if (tt < 7) stage_rows(32 * (tt + 1), 32, pb ^ 1);
            const u16* Wp = Wb0 + pb * 8192;
            const int k0 = 32 * tt;
            #pragma unroll 8
            for (int kk = 0; kk < 32; ++kk) {
                uint2 wv = *(const uint2*)(Wp + kk * 256 + c0);
                float w0 = __uint_as_float(wv.x << 16);
                float w1 = __uint_as_float(wv.x & 0xffff0000u);
                float w2 = __uint_as_float(wv.y << 16);
                float w3 = __uint_as_float(wv.y & 0xffff0000u);
                float2 xp = *(const float2*)&xsT[(k0 + kk) * 10 + 2 * w];
                acc0[0] += xp.x * w0; acc0[1] += xp.x * w1;
                acc0[2] += xp.x * w2; acc0[3] += xp.x * w3;
                acc1[0] += xp.y * w0; acc1[1] += xp.y * w1;
                acc1[2] += xp.y * w2; acc1[3] += xp.y * w3;
            }
            __syncthreads();
            pb ^= 1;
        }
        const __hip_bfloat16* ga = (const __hip_bfloat16*)gat_a + (size_t)l * 512;
        float d10 = 0.f, d20 = 0.f, d11 = 0.f, d21 = 0.f;
        #pragma unroll
        for (int j = 0; j < 4; ++j) {
            float a1v = b2f(ga[c0 + j]), a2v = b2f(ga[256 + c0 + j]);
            d10 += acc0[j] * a1v; d20 += acc0[j] * a2v;
            d11 += acc1[j] * a1v; d21 += acc1[j] * a2v;
        }
        #pragma unroll
        for (int off = 1; off < 64; off <<= 1) {
            d10 += __shfl_xor(d10, off, 64); d20 += __shfl_xor(d20, off, 64);
            d11 += __shfl_xor(d11, off, 64); d21 += __shfl_xor(d21, off, 64);
        }
        if (tx == 0) {
            s1w[row0 + 2 * w] = d10;     s2w[row0 + 2 * w] = d20;
            s1w[row0 + 2 * w + 1] = d11; s2w[row0 + 2 * w + 1] = d21;
        }
        *(float4*)&hw[(size_t)(row0 + 2 * w) * 256 + c0]     = (float4){acc0[0], acc0[1], acc0[2], acc0[3]};
        *(float4*)&hw[(size_t)(row0 + 2 * w + 1) * 256 + c0] = (float4){acc1[0], acc1[1], acc1[2], acc1[3]};
    } else {
        const float* Wlf = (const float*)gat_W + (size_t)l * 65536;
        const float* gaf = (const float*)gat_a + (size_t)l * 512;
        #pragma unroll 4
        for (int k = 0; k < 256; ++k) {
            float4 wf = *(const float4*)(Wlf + k * 256 + c0);
            float2 xp = *(const float2*)&xsT[k * 10 + 2 * w];
            acc0[0] += xp.x * wf.x; acc0[1] += xp.x * wf.y;
            acc0[2] += xp.x * wf.z; acc0[3] += xp.x * wf.w;
            acc1[0] += xp.y * wf.x; acc1[1] += xp.y * wf.y;
            acc1[2] += xp.y * wf.z; acc1[3] += xp.y * wf.w;
        }
        float d10 = 0.f, d20 = 0.f, d11 = 0.f, d21 = 0.f;
        #pragma unroll
        for (int j = 0; j < 4; ++j) {
            float a1v = gaf[c0 + j], a2v = gaf[256 + c0 + j];
            d10 += acc0[j] * a1v; d20 += acc0[j] * a2v;
            d11 += acc1[j] * a1v; d21 += acc1[j] * a2v;
        }
        #pragma unroll
        for (int off = 1; off < 64; off <<= 1) {
            d10 += __shfl_xor(d10, off, 64); d20 += __shfl_xor(d20, off, 64);
            d11 += __shfl_xor(d11, off, 64); d21 += __shfl_xor(d21, off, 64);
        }
        if (tx == 0) {
            s1w[row0 + 2 * w] = d10;     s2w[row0 + 2 * w] = d20;
            s1w[row0 + 2 * w + 1] = d11; s2w[row0 + 2 * w + 1] = d21;
        }
        *(float4*)&hw[(size_t)(row0 + 2 * w) * 256 + c0]     = (float4){acc0[0], acc0[1], acc0[2], acc0[3]};
        *(float4*)&hw[(size_t)(row0 + 2 * w + 1) * 256 + c0] = (float4){acc1[0], acc1[1], acc1[2], acc1[3]};
    }
}

// attn compute (round-1 proven): softmax(mask(leaky(s1+s2))) @ h -> ac0/ac1.
// Ends after the c-loop's final __syncthreads(); LDS is then reusable.
__device__ __forceinline__ void attn_compute(
    char* smem, int t, int b, int s,
    const float* __restrict__ hw, const float* __restrict__ s1w,
    const float* __restrict__ s2w, const int* __restrict__ adj,
    float ac0[4], float ac1[4]) {
    float (*att_t)[10] = (float (*)[10])smem;                 // 5120 B
    float* hbuf = (float*)(smem + 5120);                      // 65536 B
    const int i0 = s << 3;
    const int w = t >> 6, lane = t & 63;
    const char* hbytes = (const char*)(hw + (size_t)b * 32768);
    const int ph = s & 3;
    {
        char* lb = (char*)hbuf;
        const char* g = hbytes + ph * 32768;
        #pragma unroll
        for (int i = 0; i < 8; ++i)
            async16(g + i * 4096 + t * 16, lb + i * 4096 + t * 16);
    }
    {
        int cc0 = lane, cc1 = lane + 64;
        int ir0 = i0 + 2 * w, ir1 = ir0 + 1;
        const int* a0 = adj + (size_t)(b * 128 + ir0) * 128;
        const int* a1 = adj + (size_t)(b * 128 + ir1) * 128;
        int m00 = a0[cc0], m01 = a0[cc1], m10 = a1[cc0], m11 = a1[cc1];
        float sv0 = s1w[b * 128 + ir0], sv1 = s1w[b * 128 + ir1];
        float t0 = s2w[b * 128 + cc0],  t1 = s2w[b * 128 + cc1];
        float e00 = sv0 + t0; e00 = (e00 >= 0.f) ? e00 : 0.2f * e00;
        float e01 = sv0 + t1; e01 = (e01 >= 0.f) ? e01 : 0.2f * e01;
        float e10 = sv1 + t0; e10 = (e10 >= 0.f) ? e10 : 0.2f * e10;
        float e11 = sv1 + t1; e11 = (e11 >= 0.f) ? e11 : 0.2f * e11;
        float v00 = (m00 > 0) ? e00 : NEG_INF;
        float v01 = (m01 > 0) ? e01 : NEG_INF;
        float v10 = (m10 > 0) ? e10 : NEG_INF;
        float v11 = (m11 > 0) ? e11 : NEG_INF;
        float mx0 = fmaxf(v00, v01), mx1 = fmaxf(v10, v11);
        #pragma unroll
        for (int off = 1; off < 64; off <<= 1) {
            mx0 = fmaxf(mx0, __shfl_xor(mx0, off, 64));
            mx1 = fmaxf(mx1, __shfl_xor(mx1, off, 64));
        }
        float p00 = __expf(v00 - mx0), p01 = __expf(v01 - mx0);
        float p10 = __expf(v10 - mx1), p11 = __expf(v11 - mx1);
        float sm0 = p00 + p01, sm1 = p10 + p11;
        #pragma unroll
        for (int off = 1; off < 64; off <<= 1) {
            sm0 += __shfl_xor(sm0, off, 64);
            sm1 += __shfl_xor(sm1, off, 64);
        }
        float inv0 = 1.0f / sm0, inv1 = 1.0f / sm1;
        att_t[cc0][2 * w]     = p00 * inv0;
        att_t[cc1][2 * w]     = p01 * inv0;
        att_t[cc0][2 * w + 1] = p10 * inv1;
        att_t[cc1][2 * w + 1] = p11 * inv1;
    }
    __syncthreads();
    int tx = t & 63, ty = t >> 6;
    #pragma unroll
    for (int j = 0; j < 4; ++j) { ac0[j] = 0.f; ac1[j] = 0.f; }
    for (int c = 0; c < 4; ++c) {
        if (c < 3) {
            char* lb = (char*)hbuf + ((c + 1) & 1) * 32768;
            const char* g = hbytes + (((c + 1 + ph) & 3) * 32768);
            #pragma unroll
            for (int i = 0; i < 8; ++i)
                async16(g + i * 4096 + t * 16, lb + i * 4096 + t * 16);
        }
        const float* hc = hbuf + (c & 1) * 8192;
        const int jb = ((c + ph) & 3) * 32;
        #pragma unroll 4
        for (int jj = 0; jj < 32; ++jj) {
            float4 hv = *(const float4*)&hc[jj * 256 + 4 * tx];
            float2 ap = *(const float2*)&att_t[jb + jj][2 * ty];
            ac0[0] += ap.x * hv.x; ac0[1] += ap.x * hv.y;
            ac0[2] += ap.x * hv.z; ac0[3] += ap.x * hv.w;
            ac1[0] += ap.y * hv.x; ac1[1] += ap.y * hv.y;
            ac1[2] += ap.y * hv.z; ac1[3] += ap.y * hv.w;
        }
        __syncthreads();
    }
}

// ===========================================================================
// K1: gat layer 0 (nf@Wn+b projection prologue, proven) -> h0, s1_0, s2_0
// ===========================================================================
__global__ __launch_bounds__(256) void k_gat_first(
    const void* __restrict__ nf, const void* __restrict__ Wn_raw,
    const void* __restrict__ bn,
    const void* __restrict__ gat_W, const void* __restrict__ gat_a,
    float* __restrict__ hw, float* __restrict__ s1w, float* __restrict__ s2w) {
    __shared__ __align__(16) char smem[43008];
    const int t = threadIdx.x;
    const int row0 = blockIdx.x * 8;
    const int tx = t & 63, w = t >> 6;
    const int c0 = 4 * tx;
    float* xsT = (float*)smem;
    float acc0[4], acc1[4];

    if (sniff(Wn_raw)) {
        u16* Wb0 = (u16*)(smem + 10240);
        const u16* Wl = (const u16*)gat_W;   // layer 0
        auto stage = [&](const u16* src, int r0, int nr, int buf) {
            const char* g = (const char*)src + (size_t)r0 * 512;
            char* lp = (char*)(Wb0 + buf * 8192);
            int bytes = nr * 512;
            for (int off = t * 16; off < bytes; off += 4096)
                async16(g + off, lp + off);
        };
        auto tile = [&](int buf, int k0, int nr) {
            const u16* Wp = Wb0 + buf * 8192;
            #pragma unroll 8
            for (int kk = 0; kk < nr; ++kk) {
                uint2 wv = *(const uint2*)(Wp + kk * 256 + c0);
                float w0 = __uint_as_float(wv.x << 16);
                float w1 = __uint_as_float(wv.x & 0xffff0000u);
                float w2 = __uint_as_float(wv.y << 16);
                float w3 = __uint_as_float(wv.y & 0xffff0000u);
                float2 xp = *(const float2*)&xsT[(k0 + kk) * 10 + 2 * w];
                acc0[0] += xp.x * w0; acc0[1] += xp.x * w1;
                acc0[2] += xp.x * w2; acc0[3] += xp.x * w3;
                acc1[0] += xp.y * w0; acc1[1] += xp.y * w1;
                acc1[2] += xp.y * w2; acc1[3] += xp.y * w3;
            }
        };
        const u16* Wnl = (const u16*)Wn_raw;
        stage(Wnl, 0, 32, 0);
        const u16* nfu = (const u16*)nf;
        for (int i = t; i < 624; i += 256) {
            int r = i / 78, k = i - r * 78;
            xsT[k * 10 + r] = __uint_as_float(((unsigned)nfu[(row0 + r) * 78 + k]) << 16);
        }
        const __hip_bfloat16* bnb = (const __hip_bfloat16*)bn;
        #pragma unroll
        for (int j = 0; j < 4; ++j) { acc0[j] = b2f(bnb[c0 + j]); acc1[j] = acc0[j]; }
        __syncthreads();
        stage(Wnl, 32, 32, 1);
        tile(0, 0, 32);
        __syncthreads();
        stage(Wnl, 64, 14, 0);
        tile(1, 32, 32);
        __syncthreads();
        stage(Wl, 0, 32, 1);      // first main-W tile under last Wn tile
        tile(0, 64, 14);
        __syncthreads();
        #pragma unroll
        for (int j = 0; j < 4; ++j) {
            xsT[(c0 + j) * 10 + 2 * w]     = acc0[j];
            xsT[(c0 + j) * 10 + 2 * w + 1] = acc1[j];
        }
        __syncthreads();          // xsT ready; Wl tile0 drained, in buf1
        gat_core<1>(smem, t, row0, /*pb0=*/1, gat_W, gat_a, 0, hw, s1w, s2w);
    } else {
        const float* nff = (const float*)nf;
        for (int i = t; i < 624; i += 256) {
            int r = i / 78, k = i - r * 78;
            xsT[k * 10 + r] = nff[(row0 + r) * 78 + k];
        }
        __syncthreads();
        const float* Wnf = (const float*)Wn_raw;
        const float* bnf = (const float*)bn;
        #pragma unroll
        for (int j = 0; j < 4; ++j) { acc0[j] = bnf[c0 + j]; acc1[j] = acc0[j]; }
        for (int k = 0; k < 78; ++k) {
            float4 wf = *(const float4*)(Wnf + k * 256 + c0);
            float2 xp = *(const float2*)&xsT[k * 10 + 2 * w];
            acc0[0] += xp.x * wf.x; acc0[1] += xp.x * wf.y;
            acc0[2] += xp.x * wf.z; acc0[3] += xp.x * wf.w;
            acc1[0] += xp.y * wf.x; acc1[1] += xp.y * wf.y;
            acc1[2] += xp.y * wf.z; acc1[3] += xp.y * wf.w;
        }
        __syncthreads();
        #pragma unroll
        for (int j = 0; j < 4; ++j) {
            xsT[(c0 + j) * 10 + 2 * w]     = acc0[j];
            xsT[(c0 + j) * 10 + 2 * w + 1] = acc1[j];
        }
        __syncthreads();
        gat_core<0>(smem, t, row0, 0, gat_W, gat_a, 0, hw, s1w, s2w);
    }
}

// ===========================================================================
// K2/K3: attn layer l-1 + gat layer l, fused block-locally. The attn output
// rows/cols of thread t are exactly the xsT entries gat needs (ty==w, same
// cols), so relu'd accumulators go straight from registers into the LDS
// transpose — no global x buffer, no extra staging pass, no cross-block sync.
// ===========================================================================
__global__ __launch_bounds__(256) void k_attn_gat(
    const float* __restrict__ h_in, const float* __restrict__ s1_in,
    const float* __restrict__ s2_in, const int* __restrict__ adj,
    const void* __restrict__ gat_W, const void* __restrict__ gat_a, int l,
    const void* __restrict__ Wn_raw,
    float* __restrict__ h_out, float* __restrict__ s1_out, float* __restrict__ s2_out) {
    __shared__ __align__(16) char smem[74752];
    const int t = threadIdx.x;
    const int blk = blockIdx.x;
    const int b = blk >> 4, s = blk & 15;
    const int row0 = blk * 8;
    const int isbf = sniff(Wn_raw);

    float ac0[4], ac1[4];
    attn_compute(smem, t, b, s, h_in, s1_in, s2_in, adj, ac0, ac1);
    // last __syncthreads() of attn_compute: LDS fully dead -> reuse for gat.
    const int tx = t & 63, ty = t >> 6;
    const int c0 = 4 * tx;
    float* xsT = (float*)smem;
    if (isbf) {
        // issue W tile0 staging first so it drains at the barrier below
        u16* Wb0 = (u16*)(smem + 10240);
        const u16* Wl = (const u16*)gat_W + (size_t)l * 65536;
        for (int off = t * 16; off < 16384; off += 4096)
            async16((const char*)Wl + off, (char*)Wb0 + off);
    }
    #pragma unroll
    for (int j = 0; j < 4; ++j) {
        xsT[(c0 + j) * 10 + 2 * ty]     = fmaxf(ac0[j], 0.f);
        xsT[(c0 + j) * 10 + 2 * ty + 1] = fmaxf(ac1[j], 0.f);
    }
    __syncthreads();   // xsT visible + (bf16) W tile0 drained into buf0
    if (isbf)
        gat_core<1>(smem, t, row0, /*pb0=*/0, gat_W, gat_a, l, h_out, s1_out, s2_out);
    else
        gat_core<0>(smem, t, row0, 0, gat_W, gat_a, l, h_out, s1_out, s2_out);
}

// ===========================================================================
// K4: attn layer 2 + mean-pool partials (proven epilogue)
// ===========================================================================
__global__ __launch_bounds__(256) void k_attn_pool(
    const float* __restrict__ h_in, const float* __restrict__ s1_in,
    const float* __restrict__ s2_in, const int* __restrict__ adj,
    float* __restrict__ gpart) {
    __shared__ __align__(16) char smem[74752];
    const int t = threadIdx.x;
    const int blk = blockIdx.x;
    const int b = blk >> 4, s = blk & 15;
    float ac0[4], ac1[4];
    attn_compute(smem, t, b, s, h_in, s1_in, s2_in, adj, ac0, ac1);
    float (*pool_red)[256] = (float (*)[256])(smem + 70656);
    const int tx = t & 63, ty = t >> 6;
    float4 pr = {(fmaxf(ac0[0],0.f) + fmaxf(ac1[0],0.f)) * (1.f/128.f),
                 (fmaxf(ac0[1],0.f) + fmaxf(ac1[1],0.f)) * (1.f/128.f),
                 (fmaxf(ac0[2],0.f) + fmaxf(ac1[2],0.f)) * (1.f/128.f),
                 (fmaxf(ac0[3],0.f) + fmaxf(ac1[3],0.f)) * (1.f/128.f)};
    *(float4*)&pool_red[ty][4 * tx] = pr;
    __syncthreads();
    if (t < 64) {
        float4 r0 = ((const float4*)&pool_red[0][0])[t];
        float4 r1 = ((const float4*)&pool_red[1][0])[t];
        float4 r2 = ((const float4*)&pool_red[2][0])[t];
        float4 r3 = ((const float4*)&pool_red[3][0])[t];
        float4 o = {r0.x+r1.x+r2.x+r3.x, r0.y+r1.y+r2.y+r3.y,
                    r0.z+r1.z+r2.z+r3.z, r0.w+r1.w+r2.w+r3.w};
        *(float4*)&gpart[((size_t)b * 16 + s) * 256 + 4 * t] = o;
    }
}

// ===========================================================================
// K5: head — pool MLPs + concat + out MLP (round-1 proven body)
// ===========================================================================
template <typename T>
__device__ __forceinline__ void head_body(
    int b, int t, const float* __restrict__ gpart,
    const T* scaf, const T* W_sc, const T* b_sc,
    const T* gp_w1, const T* gp_b1, const T* gp_w2, const T* gp_b2,
    const T* out_w1, const T* out_b1, const T* out_w2, const T* out_b2,
    float* gin_s, float* sproj, float* scaf_s,
    float* red1, float* red2, float* z1g, float* z1s,
    float* cvec, float* hdn, float* outv) {
    float g = 0.f;
    #pragma unroll
    for (int gg = 0; gg < 16; ++gg) g += gpart[((size_t)b * 16 + gg) * 256 + t];
    gin_s[t] = g;
    if (t < 20) scaf_s[t] = ldv(scaf, b * 20 + t);
    __syncthreads();
    {
        float sa = ldv(b_sc, t);
        #pragma unroll
        for (int k = 0; k < 20; ++k) sa += scaf_s[k] * ldv(W_sc, k * 256 + t);
        sproj[t] = sa;
    }
    __syncthreads();
    {
        int j = t & 127, khalf = t >> 7;
        int k0 = khalf * 128;
        float a1 = 0.f, a2 = 0.f;
        #pragma unroll 16
        for (int kk = 0; kk < 128; ++kk) {
            int k = k0 + kk;
            float wv = ldv(gp_w1, k * 128 + j);
            a1 += gin_s[k] * wv;
            a2 += sproj[k] * wv;
        }
        red1[t] = a1; red2[t] = a2;
    }
    __syncthreads();
    if (t < 128) {
        float bb = ldv(gp_b1, t);
        z1g[t] = fmaxf(bb + red1[t] + red1[t + 128], 0.f);
        z1s[t] = fmaxf(bb + red2[t] + red2[t + 128], 0.f);
    }
    __syncthreads();
    {
        int j = t & 63, q = t >> 6;
        int k0 = q * 32;
        float a1 = 0.f, a2 = 0.f;
        #pragma unroll
        for (int kk = 0; kk < 32; ++kk) {
            int k = k0 + kk;
            float wv = ldv(gp_w2, k * 64 + j);
            a1 += z1g[k] * wv;
            a2 += z1s[k] * wv;
        }
        red1[t] = a1; red2[t] = a2;
    }
    __syncthreads();
    if (t < 64) {
        float bb = ldv(gp_b2, t);
        cvec[t]      = fmaxf(bb + red1[t] + red1[t + 64] + red1[t + 128] + red1[t + 192], 0.f);
        cvec[64 + t] = fmaxf(bb + red2[t] + red2[t + 64] + red2[t + 128] + red2[t + 192], 0.f);
    }
    __syncthreads();
    {
        int j = t & 127, khalf = t >> 7;
        int k0 = khalf * 64;
        float a = 0.f;
        #pragma unroll 16
        for (int kk = 0; kk < 64; ++kk) {
            int k = k0 + kk;
            a += cvec[k] * ldv(out_w1, k * 128 + j);
        }
        red1[t] = a;
    }
    __syncthreads();
    if (t < 128) hdn[t] = fmaxf(ldv(out_b1, t) + red1[t] + red1[t + 128], 0.f);
    __syncthreads();
    if (t < 13) {
        float a = ldv(out_b2, t);
        #pragma unroll 16
        for (int k = 0; k < 128; ++k) a += hdn[k] * ldv(out_w2, k * 13 + t);
        outv[t] = a;
    }
}

__global__ __launch_bounds__(256) void k_head(
    const float* __restrict__ gpart, const void* __restrict__ scaf,
    const void* __restrict__ W_sc, const void* __restrict__ b_sc,
    const void* __restrict__ gp_w1, const void* __restrict__ gp_b1,
    const void* __restrict__ gp_w2, const void* __restrict__ gp_b2,
    const void* __restrict__ out_w1, const void* __restrict__ out_b1,
    const void* __restrict__ out_w2, const void* __restrict__ out_b2,
    void* __restrict__ out, const void* __restrict__ Wn) {
    int isbf = sniff(Wn);
    int b = blockIdx.x;
    int t = threadIdx.x;
    __shared__ float gin_s[256], sproj[256], scaf_s[20];
    __shared__ float red1[256], red2[256];
    __shared__ float z1g[128], z1s[128], cvec[128], hdn[128], outv[13];
    if (isbf) {
        head_body<__hip_bfloat16>(b, t, gpart,
            (const __hip_bfloat16*)scaf, (const __hip_bfloat16*)W_sc, (const __hip_bfloat16*)b_sc,
            (const __hip_bfloat16*)gp_w1, (const __hip_bfloat16*)gp_b1,
            (const __hip_bfloat16*)gp_w2, (const __hip_bfloat16*)gp_b2,
            (const __hip_bfloat16*)out_w1, (const __hip_bfloat16*)out_b1,
            (const __hip_bfloat16*)out_w2, (const __hip_bfloat16*)out_b2,
            gin_s, sproj, scaf_s, red1, red2, z1g, z1s, cvec, hdn, outv);
    } else {
        head_body<float>(b, t, gpart,
            (const float*)scaf, (const float*)W_sc, (const float*)b_sc,
            (const float*)gp_w1, (const float*)gp_b1,
            (const float*)gp_w2, (const float*)gp_b2,
            (const float*)out_w1, (const float*)out_b1,
            (const float*)out_w2, (const float*)out_b2,
            gin_s, sproj, scaf_s, red1, red2, z1g, z1s, cvec, hdn, outv);
    }
    __syncthreads();
    if (t < 13) {
        if (isbf) ((__hip_bfloat16*)out)[b * 13 + t] = __float2bfloat16(outv[t]);
        else      ((float*)out)[b * 13 + t] = outv[t];
    }
}

extern "C" void kernel_launch(void* const* d_in, const int* in_sizes, int n_in,
                              void* d_out, int out_size, void* d_ws, size_t ws_size,
                              hipStream_t stream) {
    (void)in_sizes; (void)n_in; (void)out_size; (void)ws_size;
    const void* nf     = d_in[0];
    const int*  adj    = (const int*)d_in[2];
    const void* scaf   = d_in[3];
    const void* W_node = d_in[4];
    const void* b_node = d_in[5];
    const void* gat_W  = d_in[6];
    const void* gat_a  = d_in[7];
    const void* W_sc   = d_in[8];
    const void* b_sc   = d_in[9];
    const void* gp_w1  = d_in[10];
    const void* gp_b1  = d_in[11];
    const void* gp_w2  = d_in[12];
    const void* gp_b2  = d_in[13];
    const void* out_w1 = d_in[14];
    const void* out_b1 = d_in[15];
    const void* out_w2 = d_in[16];
    const void* out_b2 = d_in[17];

    float* ws    = (float*)d_ws;
    float* hA    = ws;                      // 1,048,576 f32
    float* hB    = ws + 1048576;            // 1,048,576 f32
    float* s1A   = ws + 2097152;            // 4096
    float* s2A   = ws + 2101248;            // 4096
    float* s1B   = ws + 2105344;            // 4096
    float* s2B   = ws + 2109440;            // 4096
    float* gpart = ws + 2113536;            // 131,072

    // K1: gat layer 0
    k_gat_first<<<512, 256, 0, stream>>>(nf, W_node, b_node, gat_W, gat_a,
                                         hA, s1A, s2A);
    // K2: attn0 + gat1 (block-local x handoff)
    k_attn_gat<<<512, 256, 0, stream>>>(hA, s1A, s2A, adj, gat_W, gat_a, 1,
                                        W_node, hB, s1B, s2B);
    // K3: attn1 + gat2
    k_attn_gat<<<512, 256, 0, stream>>>(hB, s1B, s2B, adj, gat_W, gat_a, 2,
                                        W_node, hA, s1A, s2A);
    // K4: attn2 + pool
    k_attn_pool<<<512, 256, 0, stream>>>(hA, s1A, s2A, adj, gpart);
    // K5: head
    k_head<<<32, 256, 0, stream>>>(gpart, scaf, W_sc, b_sc, gp_w1, gp_b1, gp_w2, gp_b2,
                                   out_w1, out_b1, out_w2, out_b2, d_out, W_node);
}